// Round 1
// baseline (289.963 us; speedup 1.0000x reference)
//
#include <hip/hip_runtime.h>
#include <stdint.h>

typedef _Float16 f16;
typedef f16 half2_t __attribute__((ext_vector_type(2)));
typedef f16 half4_t __attribute__((ext_vector_type(4)));
typedef f16 half8_t __attribute__((ext_vector_type(8)));
typedef __fp16 fp16x2_t __attribute__((ext_vector_type(2)));
typedef float f32x4 __attribute__((ext_vector_type(4)));

#define N_ 4
#define S_ 2048
#define D_ 1024
#define H_ 16
#define HD_ 64
#define LOG2E 1.44269504088896340736f
#define SCALE_ 0.03125f   /* 1/sqrt(1024) */

typedef __attribute__((address_space(1))) void gvoid;
typedef __attribute__((address_space(3))) void lvoid;

__device__ __forceinline__ void load_lds16(const void* g, void* l) {
  __builtin_amdgcn_global_load_lds((gvoid*)(uintptr_t)g, (lvoid*)l, 16, 0, 0);
}

__device__ __forceinline__ f32x4 mfma16(half4_t a, half4_t b, f32x4 c) {
  return __builtin_amdgcn_mfma_f32_16x16x16f16(a, b, c, 0, 0, 0);
}
__device__ __forceinline__ f32x4 mfma32(half8_t a, half8_t b, f32x4 c) {
  return __builtin_amdgcn_mfma_f32_16x16x32_f16(a, b, c, 0, 0, 0);
}

__device__ __forceinline__ half2_t pack_f16(float a, float b) {
  fp16x2_t t = __builtin_amdgcn_cvt_pkrtz(a, b);
  return __builtin_bit_cast(half2_t, t);
}

#define LO4(v) __builtin_shufflevector(v, v, 0, 1, 2, 3)
#define HI4(v) __builtin_shufflevector(v, v, 4, 5, 6, 7)

// ---------------- weight prep (Wbig + Mq) ----------------
__global__ void wprep(const float* __restrict__ Wv, const float* __restrict__ Wo,
                      const float* __restrict__ Wq, const float* __restrict__ Wk,
                      f16* __restrict__ Wbig, float* __restrict__ Mq) {
  int b = blockIdx.x;
  if (b < 1024) {
    int j = b;
#pragma unroll
    for (int c = 0; c < 4; ++c) {
      int i = c * 256 + threadIdx.x;
      int h = i >> 6, dd = i & 63;
      const float* wo = Wo + (size_t)j * 1024 + h * 64;
      float acc = 0.f;
#pragma unroll 8
      for (int e = 0; e < 64; ++e) acc += Wv[e * 64 + dd] * wo[e];
      Wbig[(size_t)j * 1024 + i] = (f16)acc;
    }
  } else {
    int tid = (b - 1024) * 256 + threadIdx.x;  // 4096 threads
    int d = tid >> 6, e = tid & 63;
    float acc = 0.f;
#pragma unroll 8
    for (int r = 0; r < 64; ++r) acc += Wq[r * 64 + d] * Wk[r * 64 + e];
    Mq[d * 64 + e] = acc * (SCALE_ * LOG2E);
  }
}

// ---------------- prep2: Q-proj + K cast (blocks 0..511), V transpose (512..4607)
__global__ __launch_bounds__(256) void prep2(const float* __restrict__ Q,
                                             const float* __restrict__ K,
                                             const float* __restrict__ V,
                                             const float* __restrict__ Mq,
                                             f16* __restrict__ q16, f16* __restrict__ k16,
                                             f16* __restrict__ v16) {
  __shared__ char smem[16384];
  int b = blockIdx.x;
  if (b < 512) {
    float* mql = (float*)smem;
#pragma unroll
    for (int c = 0; c < 16; ++c) mql[c * 256 + threadIdx.x] = Mq[c * 256 + threadIdx.x];
    __syncthreads();
    int n = b >> 7, sblk = b & 127;
    int L = threadIdx.x & 63, w = threadIdx.x >> 6;
    int lq = L & 15, hh = w * 4 + (L >> 4);
    int s = sblk * 16 + lq;
    const float* qrow = Q + ((size_t)(n * S_ + s)) * D_ + hh * HD_;
    f32x4 acc4[16];
#pragma unroll
    for (int i = 0; i < 16; ++i) acc4[i] = (f32x4){0.f, 0.f, 0.f, 0.f};
    for (int d4 = 0; d4 < 16; ++d4) {
      f32x4 qv = *(const f32x4*)(qrow + d4 * 4);
#pragma unroll
      for (int dj = 0; dj < 4; ++dj) {
        const f32x4* mrow = (const f32x4*)(mql + (d4 * 4 + dj) * 64);  // broadcast reads
        float qs = qv[dj];
#pragma unroll
        for (int i = 0; i < 16; ++i) acc4[i] += mrow[i] * qs;
      }
    }
    size_t cbase = ((size_t)((n * 16 + hh) * 128 + sblk)) * 2;
#pragma unroll
    for (int dp = 0; dp < 2; ++dp) {
#pragma unroll
      for (int qd = 0; qd < 4; ++qd) {
        half8_t hv;
        f32x4 a0 = acc4[dp * 8 + qd * 2], a1 = acc4[dp * 8 + qd * 2 + 1];
#pragma unroll
        for (int j = 0; j < 4; ++j) { hv[j] = (f16)a0[j]; hv[4 + j] = (f16)a1[j]; }
        *(half8_t*)(q16 + (cbase + dp) * 512 + (qd * 16 + lq) * 8) = hv;
      }
    }
    const float* krow = K + ((size_t)(n * S_ + s)) * D_ + hh * HD_;
    f32x4 kr[16];
#pragma unroll
    for (int i = 0; i < 16; ++i) kr[i] = *(const f32x4*)(krow + i * 4);
#pragma unroll
    for (int dp = 0; dp < 2; ++dp) {
#pragma unroll
      for (int qd = 0; qd < 4; ++qd) {
        half8_t hv;
        f32x4 a0 = kr[dp * 8 + qd * 2], a1 = kr[dp * 8 + qd * 2 + 1];
#pragma unroll
        for (int j = 0; j < 4; ++j) { hv[j] = (f16)a0[j]; hv[4 + j] = (f16)a1[j]; }
        *(half8_t*)(k16 + (cbase + dp) * 512 + (qd * 16 + lq) * 8) = hv;
      }
    }
  } else {
    f16* lv = (f16*)smem;
    int b2 = b - 512;  // 4096 = 4 n * 16 h * 64 sb32
    int n = b2 >> 10, hh = (b2 >> 6) & 15, sb = b2 & 63;
    int t = threadIdx.x;
    {
      int r = t >> 3, ic = t & 7;
      const float* src = V + ((size_t)(n * S_ + sb * 32 + r)) * D_ + hh * HD_ + ic * 8;
      f32x4 a = *(const f32x4*)src;
      f32x4 b3 = *(const f32x4*)(src + 4);
      half8_t hv;
#pragma unroll
      for (int j = 0; j < 4; ++j) { hv[j] = (f16)a[j]; hv[4 + j] = (f16)b3[j]; }
      *(half8_t*)(lv + r * 64 + ic * 8) = hv;
    }
    __syncthreads();
    {
      int mt = t >> 6, L = t & 63;
      int quad = L >> 4, ld = L & 15;
      half8_t o;
#pragma unroll
      for (int j = 0; j < 4; ++j) {
        o[j]     = lv[(quad * 4 + j) * 64 + mt * 16 + ld];
        o[4 + j] = lv[(quad * 4 + j + 16) * 64 + mt * 16 + ld];
      }
      *(half8_t*)(v16 + (((size_t)(n * 16 + hh) * 64 + sb) * 4 + mt) * 512 + L * 8) = o;
    }
  }
}

// ---------------- flash: fused phase1+phase2, K+V double-buffer, 1 barrier/iter ----
// grid (x=nh 64, y=qt2 16) -> XCD = nh%8 (K/V L2 affinity)
// OCCUPANCY VERSION: 64 k-rows per iter (K tile 8K, V tile 8K, dbuf -> 32K LDS total)
// so 4 blocks/CU co-reside (128K LDS, 16 waves/CU) instead of 2 (was 64K LDS).
// The whole 1024-block grid is resident in ONE round; 4 independent blocks per CU
// provide cross-block MFMA/VALU/LDS overlap that the serial per-wave chain
// (QK-mfma -> exp2 -> pack -> PV-mfma) cannot. s_setprio(1) wraps MFMA clusters (T5).
__global__ __launch_bounds__(256, 4) void flash(const f16* __restrict__ q16,
                                                const f16* __restrict__ k16,
                                                const f16* __restrict__ v16,
                                                f16* __restrict__ att) {
  __shared__ char lds[32768];
  int nh = blockIdx.x;   // 64 (n,h)
  int qt2 = blockIdx.y;  // 16 q-tiles of 128
  int L = threadIdx.x & 63, w = threadIdx.x >> 6;
  int lq = L & 15, quad = L >> 4;

  // q'' B-fragments for 2 slices of 16 q-rows each
  const half8_t* qg = (const half8_t*)q16;
  half8_t qB[2][2];
#pragma unroll
  for (int j = 0; j < 2; ++j) {
    size_t qc = ((size_t)(nh * 128 + qt2 * 8 + w * 2 + j)) * 2;
    qB[j][0] = qg[qc * 64 + L];
    qB[j][1] = qg[(qc + 1) * 64 + L];
  }

  f32x4 accO[2][4];
#pragma unroll
  for (int j = 0; j < 2; ++j)
#pragma unroll
    for (int i = 0; i < 4; ++i) accO[j][i] = (f32x4){0.f, 0.f, 0.f, 0.f};
  f32x4 lvec[2] = {(f32x4){0.f, 0.f, 0.f, 0.f}, (f32x4){0.f, 0.f, 0.f, 0.f}};

  const char* kg = (const char*)k16 + (size_t)nh * 262144 + w * 2048 + L * 16;
  const char* vg = (const char*)v16 + (size_t)nh * 262144 + w * 2048 + L * 16;

  // prologue: stage tiles 0 and 1 into both buffers (each tile: 8K K + 8K V)
#pragma unroll
  for (int t = 0; t < 2; ++t)
#pragma unroll
    for (int c = 0; c < 2; ++c) {
      load_lds16(kg + t * 8192 + c * 1024, lds + t * 8192 + w * 2048 + c * 1024);
      load_lds16(vg + t * 8192 + c * 1024, lds + 16384 + t * 8192 + w * 2048 + c * 1024);
    }
  __syncthreads();

  for (int it = 0; it < 32; ++it) {
    const char* kb = lds + (it & 1) * 8192;
    const char* vb = lds + 16384 + (it & 1) * 8192;
#pragma unroll
    for (int g = 0; g < 2; ++g) {
      half4_t pcg[2][2];  // [slice][mt-in-group] — only 2 pc frags alive at a time
#pragma unroll
      for (int u = 0; u < 2; ++u) {
        int mt = 2 * g + u;
        half8_t k0 = *(const half8_t*)(kb + (mt * 2 + 0) * 1024 + L * 16);
        half8_t k1 = *(const half8_t*)(kb + (mt * 2 + 1) * 1024 + L * 16);
#pragma unroll
        for (int j = 0; j < 2; ++j) {
          f32x4 a = (f32x4){0.f, 0.f, 0.f, 0.f};
          __builtin_amdgcn_s_setprio(1);
          a = mfma32(k0, qB[j][0], a);
          a = mfma32(k1, qB[j][1], a);
          __builtin_amdgcn_s_setprio(0);
          f32x4 p;
#pragma unroll
          for (int r = 0; r < 4; ++r) p[r] = __builtin_amdgcn_exp2f(a[r]);
          lvec[j] += p;
          half2_t c01 = pack_f16(p[0], p[1]);
          half2_t c23 = pack_f16(p[2], p[3]);
          pcg[j][u] = __builtin_shufflevector(c01, c23, 0, 1, 2, 3);
        }
      }
      // phase2 for k-rows [32g, 32g+32) of this tile: consumes pcg immediately
      __builtin_amdgcn_s_setprio(1);
#pragma unroll
      for (int mt2 = 0; mt2 < 4; ++mt2) {
        half8_t vf = *(const half8_t*)(vb + (g * 4 + mt2) * 1024 + L * 16);
        half4_t vlo = LO4(vf), vhi = HI4(vf);
        f32x4 a0 = accO[0][mt2], a1 = accO[1][mt2];
        a0 = mfma16(vlo, pcg[0][0], a0);
        a0 = mfma16(vhi, pcg[0][1], a0);
        a1 = mfma16(vlo, pcg[1][0], a1);
        a1 = mfma16(vhi, pcg[1][1], a1);
        accO[0][mt2] = a0; accO[1][mt2] = a1;
      }
      __builtin_amdgcn_s_setprio(0);
    }
    __syncthreads();  // readers of buf[it&1] done; drains tiles(it+1) in-flight
    if (it + 2 < 32) {  // refill just-freed buffer with tiles(it+2)
      char* dk = lds + (it & 1) * 8192 + w * 2048;
      char* dv = lds + 16384 + (it & 1) * 8192 + w * 2048;
#pragma unroll
      for (int c = 0; c < 2; ++c) {
        load_lds16(kg + (size_t)(it + 2) * 8192 + c * 1024, dk + c * 1024);
        load_lds16(vg + (size_t)(it + 2) * 8192 + c * 1024, dv + c * 1024);
      }
    }
  }

  int n = nh >> 4, h = nh & 15;
#pragma unroll
  for (int j = 0; j < 2; ++j) {
    float l = lvec[j][0] + lvec[j][1] + lvec[j][2] + lvec[j][3];
    l += __shfl_xor(l, 16, 64);
    l += __shfl_xor(l, 32, 64);
    float inv_l = 1.0f / l;
    int s = qt2 * 128 + (w * 2 + j) * 16 + lq;
    f16* orow = att + ((size_t)(n * S_ + s)) * D_ + h * HD_;
#pragma unroll
    for (int mt2 = 0; mt2 < 4; ++mt2) {
      half4_t o;
#pragma unroll
      for (int r = 0; r < 4; ++r) o[r] = (f16)(accO[j][mt2][r] * inv_l);
      *(half4_t*)(orow + mt2 * 16 + quad * 4) = o;
    }
  }
}

// ---------------- output GEMM: XOR-swizzled LDS, double-buffer, 1 barrier/iter ----
__global__ __launch_bounds__(256, 2) void ogemm(const f16* __restrict__ A, const f16* __restrict__ Bm,
                                                const float* __restrict__ bias, float* __restrict__ C) {
  __shared__ char lds[32768];  // buf[2] x (A 8K + B 8K)
  int bm = blockIdx.x, bn = blockIdx.y;
  int L = threadIdx.x & 63, w = threadIdx.x >> 6;
  int wm = w >> 1, wn = w & 1;
  int lq = L & 15, quad = L >> 4;
  int lr = L >> 2, lc = L & 3;
  int src_c = lc ^ (lr & 3);  // stage global chunk src_c into LDS slot lc
  f32x4 acc[16];
#pragma unroll
  for (int i = 0; i < 16; ++i) acc[i] = (f32x4){0.f, 0.f, 0.f, 0.f};

  const f16* ga0 = A + ((size_t)(bm * 128 + (w * 2) * 16 + lr)) * 1024 + src_c * 8;
  const f16* gb0 = Bm + ((size_t)(bn * 128 + (w * 2) * 16 + lr)) * 1024 + src_c * 8;

  // prologue: stage kt 0 and 1
#pragma unroll
  for (int t = 0; t < 2; ++t)
#pragma unroll
    for (int c = 0; c < 2; ++c) {
      load_lds16(ga0 + t * 32 + (size_t)c * 16 * 1024, lds + t * 16384 + (w * 2 + c) * 1024);
      load_lds16(gb0 + t * 32 + (size_t)c * 16 * 1024, lds + t * 16384 + 8192 + (w * 2 + c) * 1024);
    }
  __syncthreads();

  for (int kt = 0; kt < 32; ++kt) {
    const char* base = lds + (kt & 1) * 16384;
    half8_t af[4], bf[4];
#pragma unroll
    for (int t = 0; t < 4; ++t) {
      int ch = quad ^ (lq & 3);
      af[t] = *(const half8_t*)(base + (wm * 64 + t * 16 + lq) * 64 + ch * 16);
      bf[t] = *(const half8_t*)(base + 8192 + (wn * 64 + t * 16 + lq) * 64 + ch * 16);
    }
#pragma unroll
    for (int mt = 0; mt < 4; ++mt)
#pragma unroll
      for (int nt = 0; nt < 4; ++nt)
        acc[mt * 4 + nt] =
            __builtin_amdgcn_mfma_f32_16x16x32_f16(af[mt], bf[nt], acc[mt * 4 + nt], 0, 0, 0);
    __syncthreads();  // frag reads done; drains kt+1 loads (overlapped w/ MFMA)
    if (kt + 2 < 32) {
      char* dst = lds + (kt & 1) * 16384;
#pragma unroll
      for (int c = 0; c < 2; ++c) {
        load_lds16(ga0 + (kt + 2) * 32 + (size_t)c * 16 * 1024, dst + (w * 2 + c) * 1024);
        load_lds16(gb0 + (kt + 2) * 32 + (size_t)c * 16 * 1024, dst + 8192 + (w * 2 + c) * 1024);
      }
    }
  }

#pragma unroll
  for (int nt = 0; nt < 4; ++nt) {
    int col = bn * 128 + wn * 64 + nt * 16 + lq;
    float bv = bias[col];
#pragma unroll
    for (int mt = 0; mt < 4; ++mt) {
#pragma unroll
      for (int r = 0; r < 4; ++r) {
        int row = bm * 128 + wm * 64 + mt * 16 + quad * 4 + r;
        C[(size_t)row * 1024 + col] = acc[mt * 4 + nt][r] + bv;
      }
    }
  }
}

extern "C" void kernel_launch(void* const* d_in, const int* in_sizes, int n_in,
                              void* d_out, int out_size, void* d_ws, size_t ws_size,
                              hipStream_t stream) {
  const float* V  = (const float*)d_in[0];
  const float* K  = (const float*)d_in[1];
  const float* Q  = (const float*)d_in[2];
  const float* Wv = (const float*)d_in[3];
  const float* Wk = (const float*)d_in[4];
  const float* Wq = (const float*)d_in[5];
  const float* Wo = (const float*)d_in[6];
  const float* bo = (const float*)d_in[7];
  float* out = (float*)d_out;

  char* ws = (char*)d_ws;
  float* Mq  = (float*)(ws);                          // 16 KB
  f16* Wbig  = (f16*)(ws + (1ull << 20));             // 2 MB
  f16* q16   = (f16*)(ws + (3ull << 20));             // 16 MB
  f16* k16   = (f16*)(ws + (19ull << 20));            // 16 MB
  f16* v16   = (f16*)(ws + (35ull << 20));            // 16 MB
  f16* att   = (f16*)(ws + (51ull << 20));            // 16 MB -> total 67 MB

  wprep<<<1040, 256, 0, stream>>>(Wv, Wo, Wq, Wk, Wbig, Mq);
  prep2<<<4608, 256, 0, stream>>>(Q, K, V, Mq, q16, k16, v16);
  flash<<<dim3(64, 16), 256, 0, stream>>>(q16, k16, v16, att);
  ogemm<<<dim3(64, 8), 256, 0, stream>>>(att, Wbig, bo, out);
}

// Round 2
// 271.526 us; speedup vs baseline: 1.0679x; 1.0679x over previous
//
#include <hip/hip_runtime.h>
#include <stdint.h>

typedef _Float16 f16;
typedef f16 half2_t __attribute__((ext_vector_type(2)));
typedef f16 half4_t __attribute__((ext_vector_type(4)));
typedef f16 half8_t __attribute__((ext_vector_type(8)));
typedef __fp16 fp16x2_t __attribute__((ext_vector_type(2)));
typedef float f32x4 __attribute__((ext_vector_type(4)));

#define N_ 4
#define S_ 2048
#define D_ 1024
#define H_ 16
#define HD_ 64
#define LOG2E 1.44269504088896340736f
#define SCALE_ 0.03125f   /* 1/sqrt(1024) */

typedef __attribute__((address_space(1))) void gvoid;
typedef __attribute__((address_space(3))) void lvoid;

__device__ __forceinline__ void load_lds16(const void* g, void* l) {
  __builtin_amdgcn_global_load_lds((gvoid*)(uintptr_t)g, (lvoid*)l, 16, 0, 0);
}

__device__ __forceinline__ f32x4 mfma32(half8_t a, half8_t b, f32x4 c) {
  return __builtin_amdgcn_mfma_f32_16x16x32_f16(a, b, c, 0, 0, 0);
}

__device__ __forceinline__ half2_t pack_f16(float a, float b) {
  fp16x2_t t = __builtin_amdgcn_cvt_pkrtz(a, b);
  return __builtin_bit_cast(half2_t, t);
}

// ---------------- weight prep (Wbig + Mq) ----------------
__global__ void wprep(const float* __restrict__ Wv, const float* __restrict__ Wo,
                      const float* __restrict__ Wq, const float* __restrict__ Wk,
                      f16* __restrict__ Wbig, float* __restrict__ Mq) {
  int b = blockIdx.x;
  if (b < 1024) {
    int j = b;
#pragma unroll
    for (int c = 0; c < 4; ++c) {
      int i = c * 256 + threadIdx.x;
      int h = i >> 6, dd = i & 63;
      const float* wo = Wo + (size_t)j * 1024 + h * 64;
      float acc = 0.f;
#pragma unroll 8
      for (int e = 0; e < 64; ++e) acc += Wv[e * 64 + dd] * wo[e];
      Wbig[(size_t)j * 1024 + i] = (f16)acc;
    }
  } else {
    int tid = (b - 1024) * 256 + threadIdx.x;  // 4096 threads
    int d = tid >> 6, e = tid & 63;
    float acc = 0.f;
#pragma unroll 8
    for (int r = 0; r < 64; ++r) acc += Wq[r * 64 + d] * Wk[r * 64 + e];
    Mq[d * 64 + e] = acc * (SCALE_ * LOG2E);
  }
}

// ---------------- prep2: Q-proj + K cast (blocks 0..511), V transpose (512..4607)
__global__ __launch_bounds__(256) void prep2(const float* __restrict__ Q,
                                             const float* __restrict__ K,
                                             const float* __restrict__ V,
                                             const float* __restrict__ Mq,
                                             f16* __restrict__ q16, f16* __restrict__ k16,
                                             f16* __restrict__ v16) {
  __shared__ char smem[16384];
  int b = blockIdx.x;
  if (b < 512) {
    float* mql = (float*)smem;
#pragma unroll
    for (int c = 0; c < 16; ++c) mql[c * 256 + threadIdx.x] = Mq[c * 256 + threadIdx.x];
    __syncthreads();
    int n = b >> 7, sblk = b & 127;
    int L = threadIdx.x & 63, w = threadIdx.x >> 6;
    int lq = L & 15, hh = w * 4 + (L >> 4);
    int s = sblk * 16 + lq;
    const float* qrow = Q + ((size_t)(n * S_ + s)) * D_ + hh * HD_;
    f32x4 acc4[16];
#pragma unroll
    for (int i = 0; i < 16; ++i) acc4[i] = (f32x4){0.f, 0.f, 0.f, 0.f};
    for (int d4 = 0; d4 < 16; ++d4) {
      f32x4 qv = *(const f32x4*)(qrow + d4 * 4);
#pragma unroll
      for (int dj = 0; dj < 4; ++dj) {
        const f32x4* mrow = (const f32x4*)(mql + (d4 * 4 + dj) * 64);  // broadcast reads
        float qs = qv[dj];
#pragma unroll
        for (int i = 0; i < 16; ++i) acc4[i] += mrow[i] * qs;
      }
    }
    size_t cbase = ((size_t)((n * 16 + hh) * 128 + sblk)) * 2;
#pragma unroll
    for (int dp = 0; dp < 2; ++dp) {
#pragma unroll
      for (int qd = 0; qd < 4; ++qd) {
        half8_t hv;
        f32x4 a0 = acc4[dp * 8 + qd * 2], a1 = acc4[dp * 8 + qd * 2 + 1];
#pragma unroll
        for (int j = 0; j < 4; ++j) { hv[j] = (f16)a0[j]; hv[4 + j] = (f16)a1[j]; }
        *(half8_t*)(q16 + (cbase + dp) * 512 + (qd * 16 + lq) * 8) = hv;
      }
    }
    const float* krow = K + ((size_t)(n * S_ + s)) * D_ + hh * HD_;
    f32x4 kr[16];
#pragma unroll
    for (int i = 0; i < 16; ++i) kr[i] = *(const f32x4*)(krow + i * 4);
#pragma unroll
    for (int dp = 0; dp < 2; ++dp) {
#pragma unroll
      for (int qd = 0; qd < 4; ++qd) {
        half8_t hv;
        f32x4 a0 = kr[dp * 8 + qd * 2], a1 = kr[dp * 8 + qd * 2 + 1];
#pragma unroll
        for (int j = 0; j < 4; ++j) { hv[j] = (f16)a0[j]; hv[4 + j] = (f16)a1[j]; }
        *(half8_t*)(k16 + (cbase + dp) * 512 + (qd * 16 + lq) * 8) = hv;
      }
    }
  } else {
    f16* lv = (f16*)smem;
    int b2 = b - 512;  // 4096 = 4 n * 16 h * 64 sb32
    int n = b2 >> 10, hh = (b2 >> 6) & 15, sb = b2 & 63;
    int t = threadIdx.x;
    {
      int r = t >> 3, ic = t & 7;
      const float* src = V + ((size_t)(n * S_ + sb * 32 + r)) * D_ + hh * HD_ + ic * 8;
      f32x4 a = *(const f32x4*)src;
      f32x4 b3 = *(const f32x4*)(src + 4);
      half8_t hv;
#pragma unroll
      for (int j = 0; j < 4; ++j) { hv[j] = (f16)a[j]; hv[4 + j] = (f16)b3[j]; }
      *(half8_t*)(lv + r * 64 + ic * 8) = hv;
    }
    __syncthreads();
    {
      int mt = t >> 6, L = t & 63;
      int quad = L >> 4, ld = L & 15;
      half8_t o;
#pragma unroll
      for (int j = 0; j < 4; ++j) {
        o[j]     = lv[(quad * 4 + j) * 64 + mt * 16 + ld];
        o[4 + j] = lv[(quad * 4 + j + 16) * 64 + mt * 16 + ld];
      }
      *(half8_t*)(v16 + (((size_t)(n * 16 + hh) * 64 + sb) * 4 + mt) * 512 + L * 8) = o;
    }
  }
}

// ---------------- flash: fused QK+PV, K+V double-buffer, 1 barrier/iter ----------
// Round-2 structure: grid (x=nh 64, y=qt 8); block = 4 waves x 64 q-rows = 256 q-rows.
//  - PV now uses mfma_f32_16x16x32_f16: the stored vf half8 (lo = rows quad*4+{0..3}
//    of 16-k-block 2g, hi = same rows of block 2g+1) is exactly the A-fragment
//    k-slot layout (k' = quad*8+j), and concat(pcg[u=0],pcg[u=1]) is exactly the
//    matching B-fragment. Halves PV matrix-pipe issue slots vs 16x16x16.
//  - 64 q-rows/wave (4 slices): each K/V LDS byte feeds 2x the MFMA work ->
//    LDS read traffic per CU halves; 4 independent j-chains per K-fragment.
//  - 8 blocks per nh (was 16) -> k16/v16 L2 refetch halves.
// XCD note: dispatch id = x + 64*y -> id%8 = nh%8, all q-tiles of one nh share an XCD.
__global__ __launch_bounds__(256, 2) void flash(const f16* __restrict__ q16,
                                                const f16* __restrict__ k16,
                                                const f16* __restrict__ v16,
                                                f16* __restrict__ att) {
  __shared__ char lds[32768];
  int nh = blockIdx.x;   // 64 (n,h)
  int qt = blockIdx.y;   // 8 q-tiles of 256
  int L = threadIdx.x & 63, w = threadIdx.x >> 6;
  int lq = L & 15, quad = L >> 4;

  // q'' B-fragments for 4 slices of 16 q-rows each
  const half8_t* qg = (const half8_t*)q16;
  half8_t qB[4][2];
#pragma unroll
  for (int j = 0; j < 4; ++j) {
    size_t qc = ((size_t)(nh * 128 + qt * 16 + w * 4 + j)) * 2;
    qB[j][0] = qg[qc * 64 + L];
    qB[j][1] = qg[(qc + 1) * 64 + L];
  }

  f32x4 accO[4][4];
#pragma unroll
  for (int j = 0; j < 4; ++j)
#pragma unroll
    for (int i = 0; i < 4; ++i) accO[j][i] = (f32x4){0.f, 0.f, 0.f, 0.f};
  f32x4 lvec[4];
#pragma unroll
  for (int j = 0; j < 4; ++j) lvec[j] = (f32x4){0.f, 0.f, 0.f, 0.f};

  const char* kg = (const char*)k16 + (size_t)nh * 262144 + w * 2048 + L * 16;
  const char* vg = (const char*)v16 + (size_t)nh * 262144 + w * 2048 + L * 16;

  // prologue: stage tiles 0 and 1 into both buffers (each tile: 8K K + 8K V)
#pragma unroll
  for (int t = 0; t < 2; ++t)
#pragma unroll
    for (int c = 0; c < 2; ++c) {
      load_lds16(kg + t * 8192 + c * 1024, lds + t * 8192 + w * 2048 + c * 1024);
      load_lds16(vg + t * 8192 + c * 1024, lds + 16384 + t * 8192 + w * 2048 + c * 1024);
    }
  __syncthreads();

  for (int it = 0; it < 32; ++it) {
    const char* kb = lds + (it & 1) * 8192;
    const char* vb = lds + 16384 + (it & 1) * 8192;
#pragma unroll
    for (int g = 0; g < 2; ++g) {
      half4_t pcg[4][2];  // [slice][u] — P for 16-k-blocks 2g, 2g+1
#pragma unroll
      for (int u = 0; u < 2; ++u) {
        int mt = 2 * g + u;
        half8_t k0 = *(const half8_t*)(kb + (mt * 2 + 0) * 1024 + L * 16);
        half8_t k1 = *(const half8_t*)(kb + (mt * 2 + 1) * 1024 + L * 16);
#pragma unroll
        for (int j = 0; j < 4; ++j) {
          f32x4 a = (f32x4){0.f, 0.f, 0.f, 0.f};
          __builtin_amdgcn_s_setprio(1);
          a = mfma32(k0, qB[j][0], a);
          a = mfma32(k1, qB[j][1], a);
          __builtin_amdgcn_s_setprio(0);
          f32x4 p;
#pragma unroll
          for (int r = 0; r < 4; ++r) p[r] = __builtin_amdgcn_exp2f(a[r]);
          lvec[j] += p;
          half2_t c01 = pack_f16(p[0], p[1]);
          half2_t c23 = pack_f16(p[2], p[3]);
          pcg[j][u] = __builtin_shufflevector(c01, c23, 0, 1, 2, 3);
        }
      }
      // concat u=0/u=1 half4s -> the 16x16x32 B-fragment (k' = quad*8 + j)
      half8_t pb[4];
#pragma unroll
      for (int j = 0; j < 4; ++j)
        pb[j] = __builtin_shufflevector(pcg[j][0], pcg[j][1], 0, 1, 2, 3, 4, 5, 6, 7);
      // phase2 for k-rows [32g, 32g+32): one K=32 mfma per (d-block, slice)
      __builtin_amdgcn_s_setprio(1);
#pragma unroll
      for (int mt2 = 0; mt2 < 4; ++mt2) {
        half8_t vf = *(const half8_t*)(vb + (g * 4 + mt2) * 1024 + L * 16);
#pragma unroll
        for (int j = 0; j < 4; ++j)
          accO[j][mt2] = mfma32(vf, pb[j], accO[j][mt2]);
      }
      __builtin_amdgcn_s_setprio(0);
    }
    __syncthreads();  // readers of buf[it&1] done; drains tiles(it+1) in-flight
    if (it + 2 < 32) {  // refill just-freed buffer with tiles(it+2)
      char* dk = lds + (it & 1) * 8192 + w * 2048;
      char* dv = lds + 16384 + (it & 1) * 8192 + w * 2048;
#pragma unroll
      for (int c = 0; c < 2; ++c) {
        load_lds16(kg + (size_t)(it + 2) * 8192 + c * 1024, dk + c * 1024);
        load_lds16(vg + (size_t)(it + 2) * 8192 + c * 1024, dv + c * 1024);
      }
    }
  }

  int n = nh >> 4, h = nh & 15;
#pragma unroll
  for (int j = 0; j < 4; ++j) {
    float l = lvec[j][0] + lvec[j][1] + lvec[j][2] + lvec[j][3];
    l += __shfl_xor(l, 16, 64);
    l += __shfl_xor(l, 32, 64);
    float inv_l = 1.0f / l;
    int s = qt * 256 + w * 64 + j * 16 + lq;
    f16* orow = att + ((size_t)(n * S_ + s)) * D_ + h * HD_;
#pragma unroll
    for (int mt2 = 0; mt2 < 4; ++mt2) {
      half4_t o;
#pragma unroll
      for (int r = 0; r < 4; ++r) o[r] = (f16)(accO[j][mt2][r] * inv_l);
      *(half4_t*)(orow + mt2 * 16 + quad * 4) = o;
    }
  }
}

// ---------------- output GEMM: XOR-swizzled LDS, double-buffer, 1 barrier/iter ----
__global__ __launch_bounds__(256, 2) void ogemm(const f16* __restrict__ A, const f16* __restrict__ Bm,
                                                const float* __restrict__ bias, float* __restrict__ C) {
  __shared__ char lds[32768];  // buf[2] x (A 8K + B 8K)
  int bm = blockIdx.x, bn = blockIdx.y;
  int L = threadIdx.x & 63, w = threadIdx.x >> 6;
  int wm = w >> 1, wn = w & 1;
  int lq = L & 15, quad = L >> 4;
  int lr = L >> 2, lc = L & 3;
  int src_c = lc ^ (lr & 3);  // stage global chunk src_c into LDS slot lc
  f32x4 acc[16];
#pragma unroll
  for (int i = 0; i < 16; ++i) acc[i] = (f32x4){0.f, 0.f, 0.f, 0.f};

  const f16* ga0 = A + ((size_t)(bm * 128 + (w * 2) * 16 + lr)) * 1024 + src_c * 8;
  const f16* gb0 = Bm + ((size_t)(bn * 128 + (w * 2) * 16 + lr)) * 1024 + src_c * 8;

  // prologue: stage kt 0 and 1
#pragma unroll
  for (int t = 0; t < 2; ++t)
#pragma unroll
    for (int c = 0; c < 2; ++c) {
      load_lds16(ga0 + t * 32 + (size_t)c * 16 * 1024, lds + t * 16384 + (w * 2 + c) * 1024);
      load_lds16(gb0 + t * 32 + (size_t)c * 16 * 1024, lds + t * 16384 + 8192 + (w * 2 + c) * 1024);
    }
  __syncthreads();

  for (int kt = 0; kt < 32; ++kt) {
    const char* base = lds + (kt & 1) * 16384;
    half8_t af[4], bf[4];
#pragma unroll
    for (int t = 0; t < 4; ++t) {
      int ch = quad ^ (lq & 3);
      af[t] = *(const half8_t*)(base + (wm * 64 + t * 16 + lq) * 64 + ch * 16);
      bf[t] = *(const half8_t*)(base + 8192 + (wn * 64 + t * 16 + lq) * 64 + ch * 16);
    }
#pragma unroll
    for (int mt = 0; mt < 4; ++mt)
#pragma unroll
      for (int nt = 0; nt < 4; ++nt)
        acc[mt * 4 + nt] =
            __builtin_amdgcn_mfma_f32_16x16x32_f16(af[mt], bf[nt], acc[mt * 4 + nt], 0, 0, 0);
    __syncthreads();  // frag reads done; drains kt+1 loads (overlapped w/ MFMA)
    if (kt + 2 < 32) {
      char* dst = lds + (kt & 1) * 16384;
#pragma unroll
      for (int c = 0; c < 2; ++c) {
        load_lds16(ga0 + (kt + 2) * 32 + (size_t)c * 16 * 1024, dst + (w * 2 + c) * 1024);
        load_lds16(gb0 + (kt + 2) * 32 + (size_t)c * 16 * 1024, dst + 8192 + (w * 2 + c) * 1024);
      }
    }
  }

#pragma unroll
  for (int nt = 0; nt < 4; ++nt) {
    int col = bn * 128 + wn * 64 + nt * 16 + lq;
    float bv = bias[col];
#pragma unroll
    for (int mt = 0; mt < 4; ++mt) {
#pragma unroll
      for (int r = 0; r < 4; ++r) {
        int row = bm * 128 + wm * 64 + mt * 16 + quad * 4 + r;
        C[(size_t)row * 1024 + col] = acc[mt * 4 + nt][r] + bv;
      }
    }
  }
}

extern "C" void kernel_launch(void* const* d_in, const int* in_sizes, int n_in,
                              void* d_out, int out_size, void* d_ws, size_t ws_size,
                              hipStream_t stream) {
  const float* V  = (const float*)d_in[0];
  const float* K  = (const float*)d_in[1];
  const float* Q  = (const float*)d_in[2];
  const float* Wv = (const float*)d_in[3];
  const float* Wk = (const float*)d_in[4];
  const float* Wq = (const float*)d_in[5];
  const float* Wo = (const float*)d_in[6];
  const float* bo = (const float*)d_in[7];
  float* out = (float*)d_out;

  char* ws = (char*)d_ws;
  float* Mq  = (float*)(ws);                          // 16 KB
  f16* Wbig  = (f16*)(ws + (1ull << 20));             // 2 MB
  f16* q16   = (f16*)(ws + (3ull << 20));             // 16 MB
  f16* k16   = (f16*)(ws + (19ull << 20));            // 16 MB
  f16* v16   = (f16*)(ws + (35ull << 20));            // 16 MB
  f16* att   = (f16*)(ws + (51ull << 20));            // 16 MB -> total 67 MB

  wprep<<<1040, 256, 0, stream>>>(Wv, Wo, Wq, Wk, Wbig, Mq);
  prep2<<<4608, 256, 0, stream>>>(Q, K, V, Mq, q16, k16, v16);
  flash<<<dim3(64, 8), 256, 0, stream>>>(q16, k16, v16, att);
  ogemm<<<dim3(64, 8), 256, 0, stream>>>(att, Wbig, bo, out);
}